// Round 8
// baseline (583.301 us; speedup 1.0000x reference)
//
#include <hip/hip_runtime.h>
#include <hip/hip_bf16.h>
#include <stdint.h>

#define BB 2
#define SB 2048
#define DD 512
#define HH 4
#define VV 32000

typedef __attribute__((ext_vector_type(4))) float f32x4;
typedef __attribute__((ext_vector_type(8))) short bf16x8;
typedef __attribute__((ext_vector_type(4))) unsigned short us4;

__device__ __forceinline__ unsigned short f2bf(float f) {
    unsigned u = __float_as_uint(f);
    u += 0x7fffu + ((u >> 16) & 1u);
    return (unsigned short)(u >> 16);
}

__device__ __forceinline__ __attribute__((address_space(3))) unsigned int*
as_lds(void* p) {
    return (__attribute__((address_space(3))) unsigned int*)(unsigned)(uintptr_t)p;
}
__device__ __forceinline__ const __attribute__((address_space(1))) unsigned int*
as_gbl(const void* p) {
    return (const __attribute__((address_space(1))) unsigned int*)(uintptr_t)p;
}

// swizzled read from a [rows][64] bf16 LDS tile (128B rows): logical 16B-chunk c
// lives at slot c^(row&7). 16 lanes (same c, rows r..r+15) hit 8 slots x2 = 2-way free.
__device__ __forceinline__ bf16x8 ldsrd64(const unsigned short* base, int row, int c) {
    return *(const bf16x8*)((const char*)base + row * 128 + ((c ^ (row & 7)) << 4));
}

// ---------------- merged prep kernel ----------------
__global__ void k_prep(const int* __restrict__ ids, const float* __restrict__ tbl,
                       const float* __restrict__ als,
                       const float* __restrict__ fw, const float* __restrict__ ow,
                       unsigned short* __restrict__ outw_bf, unsigned short* __restrict__ fusw_bf,
                       unsigned short* __restrict__ emb, unsigned short* __restrict__ embT,
                       float* __restrict__ dtab, float* __restrict__ lsum)
{
    __shared__ unsigned short TT[64][72];
    const int bid = blockIdx.x, t = threadIdx.x;

    if (bid < 2000) {
        int base = bid * 8192 + t * 4;
#pragma unroll
        for (int it = 0; it < 8; ++it) {
            int i = base + it * 1024;
            float4 v = *(const float4*)(ow + i);
            us4 o; o.x = f2bf(v.x); o.y = f2bf(v.y); o.z = f2bf(v.z); o.w = f2bf(v.w);
            *(us4*)(outw_bf + i) = o;
        }
    } else if (bid < 2256) {
        int base = (bid - 2000) * 4096 + t * 4;
#pragma unroll
        for (int it = 0; it < 4; ++it) {
            int i = base + it * 1024;
            float4 v = *(const float4*)(fw + i);
            us4 o; o.x = f2bf(v.x); o.y = f2bf(v.y); o.z = f2bf(v.z); o.w = f2bf(v.w);
            *(us4*)(fusw_bf + i) = o;
        }
    } else if (bid < 6352) {
        int row = bid - 2256;
        int id = ids[row];
        if (id < 0) id = 0;
        if (id >= VV) id = VV - 1;
        const float* s = tbl + (size_t)id * DD;
        unsigned short* d = emb + (size_t)row * DD;
        d[t]       = f2bf(s[t]);
        d[t + 256] = f2bf(s[t + 256]);
    } else if (bid < 6448) {
        int i = (bid - 6352) * 256 + t;
        if (i < HH * SB) {
            int h = i >> 11, dd = i & (SB - 1);
            dtab[i] = 0.04419417382415922f / (1.f + als[h] * (float)dd);
        } else {
            lsum[i - HH * SB] = 0.f;
        }
    } else {
        int bid2 = bid - 6448;
        const int d0 = (bid2 & 7) * 64, s0 = ((bid2 >> 3) & 31) * 64, b = bid2 >> 8;
        {
            int s = t >> 2, c16 = (t & 3) * 16;
            int id = ids[b * SB + s0 + s];
            if (id < 0) id = 0;
            if (id >= VV) id = VV - 1;
            const float* src = tbl + (size_t)id * DD + d0 + c16;
#pragma unroll
            for (int q4 = 0; q4 < 4; ++q4) {
                float4 v = *(const float4*)(src + q4 * 4);
                TT[c16 + q4 * 4 + 0][s] = f2bf(v.x);
                TT[c16 + q4 * 4 + 1][s] = f2bf(v.y);
                TT[c16 + q4 * 4 + 2][s] = f2bf(v.z);
                TT[c16 + q4 * 4 + 3][s] = f2bf(v.w);
            }
        }
        __syncthreads();
        {
            int d = t >> 2, sc = (t & 3) * 16;
            bf16x8 o0, o1;
#pragma unroll
            for (int j = 0; j < 8; ++j) {
                o0[j] = (short)TT[d][sc + j];
                o1[j] = (short)TT[d][sc + 8 + j];
            }
            unsigned short* dst = embT + ((size_t)(b * DD + d0 + d)) * SB + s0 + sc;
            *(bf16x8*)dst = o0;
            *(bf16x8*)(dst + 8) = o1;
        }
    }
}

// ---------------- phase 2: shared base QK^T -> per-head P tiles + row sums ----------------
__launch_bounds__(256, 2)
__global__ void k_base(const unsigned short* __restrict__ emb,
                       const unsigned char* __restrict__ pad,
                       const float* __restrict__ sfs,
                       const float* __restrict__ dtab,
                       unsigned short* __restrict__ P,      // [4][2][2048][2048]
                       float* __restrict__ lsum)            // [4][2][2048]
{
    const int kt = blockIdx.x, qt = blockIdx.y, b = blockIdx.z;
    if (kt > qt + 1) return;
    const int tid = threadIdx.x, lane = tid & 63, wv = tid >> 6;
    const int l15 = lane & 15, g = lane >> 4;

    if (kt == qt + 1) {
        int row = tid >> 2, cb = (tid & 3) * 16;
        int4 z = {0, 0, 0, 0};
#pragma unroll
        for (int h = 0; h < 4; ++h) {
            unsigned short* Ph = P + (((size_t)(h * 2 + b)) * SB + qt * 64 + row) * SB + kt * 64 + cb;
            *(int4*)Ph = z;
            *(int4*)(Ph + 8) = z;
        }
        return;
    }

    __shared__ __align__(16) unsigned short Ql[64 * 128];
    __shared__ __align__(16) unsigned short Kl[64 * 128];

    const int q = qt * 64 + wv * 16 + l15;

    f32x4 zero4 = {0.f, 0.f, 0.f, 0.f};
    f32x4 cc[4];
#pragma unroll
    for (int c = 0; c < 4; ++c) cc[c] = zero4;

    for (int dc = 0; dc < 4; ++dc) {
        const int d0 = dc * 128;
        __syncthreads();
#pragma unroll
        for (int i = 0; i < 4; ++i) {
            int flat = (i * 256 + tid) * 8;
            int row = flat >> 7;
            int ch  = (flat >> 3) & 15;
            int scol = ((ch ^ (row & 15)) << 3);
            __builtin_amdgcn_global_load_lds(
                as_gbl(emb + ((size_t)(b * SB + qt * 64 + row)) * DD + d0 + scol),
                as_lds(Ql + flat), 16, 0, 0);
            __builtin_amdgcn_global_load_lds(
                as_gbl(emb + ((size_t)(b * SB + kt * 64 + row)) * DD + d0 + scol),
                as_lds(Kl + flat), 16, 0, 0);
        }
        asm volatile("s_waitcnt vmcnt(0)" ::: "memory");
        __syncthreads();

#pragma unroll
        for (int dsl = 0; dsl < 4; ++dsl) {
            int chr = (dsl * 4 + g);
            bf16x8 qf = *(const bf16x8*)(Ql + (wv * 16 + l15) * 128 + ((chr ^ l15) << 3));
#pragma unroll
            for (int c = 0; c < 4; ++c) {
                bf16x8 kf = *(const bf16x8*)(Kl + (c * 16 + l15) * 128 + ((chr ^ l15) << 3));
                cc[c] = __builtin_amdgcn_mfma_f32_16x16x32_bf16(kf, qf, cc[c], 0, 0, 0);
            }
        }
    }

    unsigned long long padm = __ballot(pad[(size_t)b * SB + kt * 64 + lane] != 0);

    const int wins[4] = {1 << 30, 128, 512, 1 << 30};
#pragma unroll
    for (int h = 0; h < 4; ++h) {
        const int win = wins[h];
        if (kt * 64 + win + 192 < qt * 64) continue;
        const float sf = sfs[h];
        const float* dth = dtab + h * SB;
        float rsum = 0.f;
        unsigned short pb[4][4];
#pragma unroll
        for (int c = 0; c < 4; ++c) {
#pragma unroll
            for (int r = 0; r < 4; ++r) {
                int kk = kt * 64 + c * 16 + 4 * g + r;
                int dist = q - kk;
                float p = 0.f;
                if (dist >= 0 && dist <= win &&
                    ((dist == 0) || !((padm >> (c * 16 + 4 * g + r)) & 1ull))) {
                    float s = cc[c][r] * dth[dist];
                    if (dist == 0) s *= sf;
                    p = __expf(s);
                }
                rsum += p;
                pb[c][r] = f2bf(p);
            }
        }
        unsigned short* Ph = P + (((size_t)(h * 2 + b)) * SB + q) * SB + kt * 64;
#pragma unroll
        for (int c = 0; c < 4; ++c) {
            us4 o;
            o.x = pb[c][0]; o.y = pb[c][1]; o.z = pb[c][2]; o.w = pb[c][3];
            *(us4*)(Ph + c * 16 + 4 * g) = o;
        }
        rsum += __shfl_xor(rsum, 16, 64);
        rsum += __shfl_xor(rsum, 32, 64);
        if (lane < 16)
            atomicAdd(&lsum[((size_t)(h * 2 + b)) * SB + q], rsum);
    }
}

// ---------------- phase 3: ctx = P * V^T, normalize, write concat ----------------
__launch_bounds__(256, 2)
__global__ void k_pv(const unsigned short* __restrict__ P,
                     const unsigned short* __restrict__ embT,
                     const float* __restrict__ lsum,
                     unsigned short* __restrict__ concat)
{
    const int t64 = blockIdx.x, b = blockIdx.y, h = blockIdx.z;
    const int mt = t64 >> 2, nt = t64 & 3;
    const int Q0 = mt * 128;
    const int win = (h == 1) ? 128 : (h == 2) ? 512 : (1 << 30);
    int klo = Q0 - win - 64; if (klo < 0) klo = 0; klo &= ~63;
    const int khi = Q0 + 128;

    __shared__ __align__(16) unsigned short Al[128 * 32];
    __shared__ __align__(16) unsigned short Bl[128 * 32];

    const int tid = threadIdx.x, lane = tid & 63, wv = tid >> 6;
    const int wm = (wv >> 1) * 64, wn = (wv & 1) * 64;
    const int l15 = lane & 15, g = lane >> 4;

    f32x4 zero4 = {0.f, 0.f, 0.f, 0.f};
    f32x4 acc[4][4];
#pragma unroll
    for (int i = 0; i < 4; ++i)
#pragma unroll
        for (int j = 0; j < 4; ++j) acc[i][j] = zero4;

    const unsigned short* Ab = P + (((size_t)(h * 2 + b)) * SB + Q0) * SB;
    const unsigned short* Bb = embT + ((size_t)(b * DD + nt * 128)) * SB;

    for (int k0 = klo; k0 < khi; k0 += 32) {
        __syncthreads();
#pragma unroll
        for (int s = 0; s < 2; ++s) {
            int e = (s * 256 + tid) * 8;
            int row = e >> 5, col = e & 31;
            __builtin_amdgcn_global_load_lds(as_gbl(Ab + (size_t)row * SB + k0 + col),
                                             as_lds(Al + e), 16, 0, 0);
            __builtin_amdgcn_global_load_lds(as_gbl(Bb + (size_t)row * SB + k0 + col),
                                             as_lds(Bl + e), 16, 0, 0);
        }
        asm volatile("s_waitcnt vmcnt(0)" ::: "memory");
        __syncthreads();

        bf16x8 af[4], bfr[4];
#pragma unroll
        for (int i = 0; i < 4; ++i) {
            af[i]  = *(const bf16x8*)(Al + (wm + i * 16 + l15) * 32 + 8 * g);
            bfr[i] = *(const bf16x8*)(Bl + (wn + i * 16 + l15) * 32 + 8 * g);
        }
#pragma unroll
        for (int i = 0; i < 4; ++i)
#pragma unroll
            for (int j = 0; j < 4; ++j)
                acc[i][j] = __builtin_amdgcn_mfma_f32_16x16x32_bf16(af[i], bfr[j], acc[i][j], 0, 0, 0);
    }

    const float* ls = lsum + ((size_t)(h * 2 + b)) * SB;
    unsigned short* cb = concat + ((size_t)(b * SB)) * (HH * DD) + h * DD + nt * 128;
#pragma unroll
    for (int i = 0; i < 4; ++i) {
        int rowb = wm + i * 16 + g * 4;
        float inv[4];
#pragma unroll
        for (int rr = 0; rr < 4; ++rr) inv[rr] = 1.f / ls[Q0 + rowb + rr];
#pragma unroll
        for (int j = 0; j < 4; ++j) {
            int col = wn + j * 16 + l15;
#pragma unroll
            for (int rr = 0; rr < 4; ++rr)
                cb[(size_t)(Q0 + rowb + rr) * (HH * DD) + col] = f2bf(acc[i][j][rr] * inv[rr]);
        }
    }
}

// ---------------- m97-style 128x128 GEMM (fusion GEMM) ----------------
template <int OUTF32>
__launch_bounds__(256, 2)
__global__ void k_gemm_bt(const unsigned short* __restrict__ A,
                          const unsigned short* __restrict__ Bt,
                          const float* __restrict__ bias,
                          void* __restrict__ Cout,
                          int M, int N, int K)
{
    const int nMt = M >> 7;
    const int nwg = gridDim.x;
    int bid = blockIdx.x;
    int q = nwg >> 3, r = nwg & 7;
    int x = bid & 7, o = bid >> 3;
    int wg = (x < r ? x * (q + 1) : r * (q + 1) + (x - r) * q) + o;
    const int mt = wg % nMt, nt = wg / nMt;

    __shared__ __align__(16) unsigned short Al[128 * 32];
    __shared__ __align__(16) unsigned short Bl[128 * 32];

    const int tid = threadIdx.x;
    const int lane = tid & 63;
    const int wv = tid >> 6;
    const int wm = (wv >> 1) * 64, wn = (wv & 1) * 64;
    const int l15 = lane & 15, g = lane >> 4;

    f32x4 zero4 = {0.f, 0.f, 0.f, 0.f};
    f32x4 acc[4][4];
#pragma unroll
    for (int i = 0; i < 4; ++i)
#pragma unroll
        for (int j = 0; j < 4; ++j) acc[i][j] = zero4;

    const unsigned short* Ab = A + (size_t)mt * 128 * K;
    const unsigned short* Bb = Bt + (size_t)nt * 128 * K;

    for (int k0 = 0; k0 < K; k0 += 32) {
        __syncthreads();
#pragma unroll
        for (int s = 0; s < 2; ++s) {
            int e = (s * 256 + tid) * 8;
            int row = e >> 5, col = e & 31;
            __builtin_amdgcn_global_load_lds(as_gbl(Ab + (size_t)row * K + k0 + col),
                                             as_lds(Al + e), 16, 0, 0);
            __builtin_amdgcn_global_load_lds(as_gbl(Bb + (size_t)row * K + k0 + col),
                                             as_lds(Bl + e), 16, 0, 0);
        }
        asm volatile("s_waitcnt vmcnt(0)" ::: "memory");
        __syncthreads();

        bf16x8 af[4], bfr[4];
#pragma unroll
        for (int i = 0; i < 4; ++i) {
            af[i]  = *(const bf16x8*)(Al + (wm + i * 16 + l15) * 32 + 8 * g);
            bfr[i] = *(const bf16x8*)(Bl + (wn + i * 16 + l15) * 32 + 8 * g);
        }
#pragma unroll
        for (int i = 0; i < 4; ++i)
#pragma unroll
            for (int j = 0; j < 4; ++j)
                acc[i][j] = __builtin_amdgcn_mfma_f32_16x16x32_bf16(af[i], bfr[j], acc[i][j], 0, 0, 0);
    }

#pragma unroll
    for (int i = 0; i < 4; ++i) {
        int rowb = mt * 128 + wm + i * 16 + g * 4;
#pragma unroll
        for (int j = 0; j < 4; ++j) {
            int col = nt * 128 + wn + j * 16 + l15;
            float bv = bias[col];
            if (OUTF32) {
                float* C = (float*)Cout;
#pragma unroll
                for (int rr = 0; rr < 4; ++rr)
                    C[(size_t)(rowb + rr) * N + col] = acc[i][j][rr] + bv;
            } else {
                unsigned short* C = (unsigned short*)Cout;
#pragma unroll
                for (int rr = 0; rr < 4; ++rr)
                    C[(size_t)(rowb + rr) * N + col] = f2bf(acc[i][j][rr] + bv);
            }
        }
    }
}

// ---------------- logits GEMM: 256x256 tile, BK=64, double-buffer ----------------
__launch_bounds__(512, 1)
__global__ void k_logits(const unsigned short* __restrict__ A,
                         const unsigned short* __restrict__ Bt,
                         const float* __restrict__ bias,
                         float* __restrict__ Cout,
                         int M, int N, int K)
{
    const int nMt = M >> 8;
    const int nwg = gridDim.x;
    int bid = blockIdx.x;
    int q = nwg >> 3, r = nwg & 7;
    int x = bid & 7, o = bid >> 3;
    int wg = (x < r ? x * (q + 1) : r * (q + 1) + (x - r) * q) + o;
    const int mt = wg % nMt, nt = wg / nMt;

    __shared__ __align__(16) char smem[131072];

    const int tid = threadIdx.x, lane = tid & 63, wv = tid >> 6;
    const int wr = wv >> 2, wc = wv & 3;
    const int l15 = lane & 15, g = lane >> 4;

    f32x4 zero4 = {0.f, 0.f, 0.f, 0.f};
    f32x4 acc[8][4];
#pragma unroll
    for (int i = 0; i < 8; ++i)
#pragma unroll
        for (int j = 0; j < 4; ++j) acc[i][j] = zero4;

    const unsigned short* Ab = A + (size_t)mt * 256 * K;
    const unsigned short* Bb = Bt + (size_t)nt * 256 * K;

    const unsigned short* As[4];
    const unsigned short* Bs[4];
    int ldstA[4], ldstB[4];
#pragma unroll
    for (int j = 0; j < 4; ++j) {
        int ch = tid + j * 512;
        int row = ch >> 3, cpos = ch & 7;
        int scol = ((cpos ^ (row & 7)) << 3);
        As[j] = Ab + (size_t)row * K + scol;
        Bs[j] = Bb + (size_t)row * K + scol;
        ldstA[j] = ch * 16;                  // byte offset within A half
        ldstB[j] = 65536 + ch * 16;          // byte offset within B half
    }

#define STG(bufi_, k0_) {                                                              \
    _Pragma("unroll")                                                                  \
    for (int j = 0; j < 4; ++j)                                                        \
        __builtin_amdgcn_global_load_lds(as_gbl(As[j] + (k0_)),                        \
            as_lds(smem + (bufi_) * 32768 + ldstA[j]), 16, 0, 0);                      \
    _Pragma("unroll")                                                                  \
    for (int j = 0; j < 4; ++j)                                                        \
        __builtin_amdgcn_global_load_lds(as_gbl(Bs[j] + (k0_)),                        \
            as_lds(smem + (bufi_) * 32768 + ldstB[j]), 16, 0, 0); }

    STG(0, 0);
    __syncthreads();

    for (int t = 0; t < 8; ++t) {
        const int cur = t & 1;
        if (t < 7) STG(cur ^ 1, (t + 1) * 64);
        const unsigned short* Ar = (const unsigned short*)(smem + cur * 32768);
        const unsigned short* Br = (const unsigned short*)(smem + cur * 32768 + 65536);
#pragma unroll
        for (int s = 0; s < 2; ++s) {
            bf16x8 bf[4], af[8];
#pragma unroll
            for (int n = 0; n < 4; ++n)
                bf[n] = ldsrd64(Br, wc * 64 + n * 16 + l15, s * 4 + g);
#pragma unroll
            for (int m = 0; m < 8; ++m)
                af[m] = ldsrd64(Ar, wr * 128 + m * 16 + l15, s * 4 + g);
            __builtin_amdgcn_s_setprio(1);
#pragma unroll
            for (int m = 0; m < 8; ++m)
#pragma unroll
                for (int n = 0; n < 4; ++n)
                    acc[m][n] = __builtin_amdgcn_mfma_f32_16x16x32_bf16(af[m], bf[n], acc[m][n], 0, 0, 0);
            __builtin_amdgcn_s_setprio(0);
        }
        __syncthreads();
    }
#undef STG

    // ---- epilogue: LDS-staged, full-line coalesced f32 stores ----
    const int mrow = mt * 256;
    const int ncol = nt * 256;
    float* Cl = (float*)smem;
    float bvj[4];
#pragma unroll
    for (int j = 0; j < 4; ++j) bvj[j] = bias[ncol + wc * 64 + j * 16 + l15];
    const int srow = tid >> 4;            // 0..31
    const int scol = (tid & 15) * 4;      // 0..60 step 4
    const float* Crd = Cl + srow * 258 + scol;
#pragma unroll
    for (int mc = 0; mc < 8; ++mc) {
        if (wr == (mc >> 2)) {
            int ibase = (mc & 3) * 2;
#pragma unroll
            for (int ii = 0; ii < 2; ++ii) {
                int i = ibase + ii;
                int lr = ii * 16 + g * 4;
#pragma unroll
                for (int j = 0; j < 4; ++j)
#pragma unroll
                    for (int rr = 0; rr < 4; ++rr)
                        Cl[(lr + rr) * 258 + wc * 64 + j * 16 + l15] = acc[i][j][rr] + bvj[j];
            }
        }
        __syncthreads();
        {
            float* gp = Cout + (size_t)(mrow + mc * 32 + srow) * N + ncol + scol;
#pragma unroll
            for (int it = 0; it < 4; ++it)
                *(float4*)(gp + it * 64) = *(const float4*)(Crd + it * 64);
        }
        __syncthreads();
    }
}

extern "C" void kernel_launch(void* const* d_in, const int* in_sizes, int n_in,
                              void* d_out, int out_size, void* d_ws, size_t ws_size,
                              hipStream_t stream)
{
    const int*           ids = (const int*)d_in[0];
    const unsigned char* pad = (const unsigned char*)d_in[1];
    const float*         tbl = (const float*)d_in[2];
    const float*         sfs = (const float*)d_in[3];
    const float*         als = (const float*)d_in[4];
    const float*         fw  = (const float*)d_in[5];
    const float*         fb  = (const float*)d_in[6];
    const float*         ow  = (const float*)d_in[7];
    const float*         ob  = (const float*)d_in[8];
    float* logits = (float*)d_out;

    // d_ws layout (60 MB)
    char* ws = (char*)d_ws;
    unsigned short* outw_bf = (unsigned short*)(ws);              // 32,768,000 B
    unsigned short* fusw_bf = (unsigned short*)(ws + 32768000);   //  2,097,152 B
    unsigned short* emb_bf  = (unsigned short*)(ws + 34865152);   //  4,194,304 B
    unsigned short* concat  = (unsigned short*)(ws + 39059456);   // 16,777,216 B
    unsigned short* fused   = (unsigned short*)(ws + 55836672);   //  4,194,304 B

    // scratch inside d_out (dead until final GEMM overwrites it)
    char* ob_scratch = (char*)d_out;
    unsigned short* P    = (unsigned short*)(ob_scratch);              // 67,108,864 B
    unsigned short* embT = (unsigned short*)(ob_scratch + 67108864);   //  4,194,304 B
    float*          dtab = (float*)(ob_scratch + 71303168);            //     32,768 B
    float*          lsum = (float*)(ob_scratch + 71335936);            //     65,536 B

    k_prep<<<6960, 256, 0, stream>>>(ids, tbl, als, fw, ow,
                                     outw_bf, fusw_bf, emb_bf, embT, dtab, lsum);

    dim3 bg(32, 32, BB);
    k_base<<<bg, 256, 0, stream>>>(emb_bf, pad, sfs, dtab, P, lsum);

    dim3 pg(64, BB, HH);
    k_pv<<<pg, 256, 0, stream>>>(P, embT, lsum, concat);

    k_gemm_bt<0><<<32 * 4, 256, 0, stream>>>(concat, fusw_bf, fb, fused, BB * SB, DD, HH * DD);

    // MEASUREMENT: launch k_logits twice; T_logits(warm) = dur_us - 373.1
    k_logits<<<16 * 125, 512, 0, stream>>>(fused, outw_bf, ob, logits, BB * SB, VV, DD);
    k_logits<<<16 * 125, 512, 0, stream>>>(fused, outw_bf, ob, logits, BB * SB, VV, DD);
}

// Round 9
// 450.224 us; speedup vs baseline: 1.2956x; 1.2956x over previous
//
#include <hip/hip_runtime.h>
#include <hip/hip_bf16.h>
#include <stdint.h>

#define BB 2
#define SB 2048
#define DD 512
#define HH 4
#define VV 32000

typedef __attribute__((ext_vector_type(4))) float f32x4;
typedef __attribute__((ext_vector_type(8))) short bf16x8;
typedef __attribute__((ext_vector_type(4))) unsigned short us4;

__device__ __forceinline__ unsigned short f2bf(float f) {
    unsigned u = __float_as_uint(f);
    u += 0x7fffu + ((u >> 16) & 1u);
    return (unsigned short)(u >> 16);
}

__device__ __forceinline__ __attribute__((address_space(3))) unsigned int*
as_lds(void* p) {
    return (__attribute__((address_space(3))) unsigned int*)(unsigned)(uintptr_t)p;
}
__device__ __forceinline__ const __attribute__((address_space(1))) unsigned int*
as_gbl(const void* p) {
    return (const __attribute__((address_space(1))) unsigned int*)(uintptr_t)p;
}

// swizzled read from a [rows][32] bf16 LDS tile (64B rows, 4 chunks):
// logical 16B-chunk c lives at slot c^(row&3).
__device__ __forceinline__ bf16x8 ldsrd32(const unsigned short* base, int row, int c) {
    return *(const bf16x8*)((const char*)base + row * 64 + (((c) ^ (row & 3)) << 4));
}

// ---------------- merged prep kernel ----------------
__global__ void k_prep(const int* __restrict__ ids, const float* __restrict__ tbl,
                       const float* __restrict__ als,
                       const float* __restrict__ fw, const float* __restrict__ ow,
                       unsigned short* __restrict__ outw_bf, unsigned short* __restrict__ fusw_bf,
                       unsigned short* __restrict__ emb, unsigned short* __restrict__ embT,
                       float* __restrict__ dtab, float* __restrict__ lsum)
{
    __shared__ unsigned short TT[64][72];
    const int bid = blockIdx.x, t = threadIdx.x;

    if (bid < 2000) {
        int base = bid * 8192 + t * 4;
#pragma unroll
        for (int it = 0; it < 8; ++it) {
            int i = base + it * 1024;
            float4 v = *(const float4*)(ow + i);
            us4 o; o.x = f2bf(v.x); o.y = f2bf(v.y); o.z = f2bf(v.z); o.w = f2bf(v.w);
            *(us4*)(outw_bf + i) = o;
        }
    } else if (bid < 2256) {
        int base = (bid - 2000) * 4096 + t * 4;
#pragma unroll
        for (int it = 0; it < 4; ++it) {
            int i = base + it * 1024;
            float4 v = *(const float4*)(fw + i);
            us4 o; o.x = f2bf(v.x); o.y = f2bf(v.y); o.z = f2bf(v.z); o.w = f2bf(v.w);
            *(us4*)(fusw_bf + i) = o;
        }
    } else if (bid < 6352) {
        int row = bid - 2256;
        int id = ids[row];
        if (id < 0) id = 0;
        if (id >= VV) id = VV - 1;
        const float* s = tbl + (size_t)id * DD;
        unsigned short* d = emb + (size_t)row * DD;
        d[t]       = f2bf(s[t]);
        d[t + 256] = f2bf(s[t + 256]);
    } else if (bid < 6448) {
        int i = (bid - 6352) * 256 + t;
        if (i < HH * SB) {
            int h = i >> 11, dd = i & (SB - 1);
            dtab[i] = 0.04419417382415922f / (1.f + als[h] * (float)dd);
        } else {
            lsum[i - HH * SB] = 0.f;
        }
    } else {
        int bid2 = bid - 6448;
        const int d0 = (bid2 & 7) * 64, s0 = ((bid2 >> 3) & 31) * 64, b = bid2 >> 8;
        {
            int s = t >> 2, c16 = (t & 3) * 16;
            int id = ids[b * SB + s0 + s];
            if (id < 0) id = 0;
            if (id >= VV) id = VV - 1;
            const float* src = tbl + (size_t)id * DD + d0 + c16;
#pragma unroll
            for (int q4 = 0; q4 < 4; ++q4) {
                float4 v = *(const float4*)(src + q4 * 4);
                TT[c16 + q4 * 4 + 0][s] = f2bf(v.x);
                TT[c16 + q4 * 4 + 1][s] = f2bf(v.y);
                TT[c16 + q4 * 4 + 2][s] = f2bf(v.z);
                TT[c16 + q4 * 4 + 3][s] = f2bf(v.w);
            }
        }
        __syncthreads();
        {
            int d = t >> 2, sc = (t & 3) * 16;
            bf16x8 o0, o1;
#pragma unroll
            for (int j = 0; j < 8; ++j) {
                o0[j] = (short)TT[d][sc + j];
                o1[j] = (short)TT[d][sc + 8 + j];
            }
            unsigned short* dst = embT + ((size_t)(b * DD + d0 + d)) * SB + s0 + sc;
            *(bf16x8*)dst = o0;
            *(bf16x8*)(dst + 8) = o1;
        }
    }
}

// ---------------- phase 2: shared base QK^T -> per-head P tiles + row sums ----------------
__launch_bounds__(256, 2)
__global__ void k_base(const unsigned short* __restrict__ emb,
                       const unsigned char* __restrict__ pad,
                       const float* __restrict__ sfs,
                       const float* __restrict__ dtab,
                       unsigned short* __restrict__ P,      // [4][2][2048][2048]
                       float* __restrict__ lsum)            // [4][2][2048]
{
    const int kt = blockIdx.x, qt = blockIdx.y, b = blockIdx.z;
    if (kt > qt + 1) return;
    const int tid = threadIdx.x, lane = tid & 63, wv = tid >> 6;
    const int l15 = lane & 15, g = lane >> 4;

    if (kt == qt + 1) {
        int row = tid >> 2, cb = (tid & 3) * 16;
        int4 z = {0, 0, 0, 0};
#pragma unroll
        for (int h = 0; h < 4; ++h) {
            unsigned short* Ph = P + (((size_t)(h * 2 + b)) * SB + qt * 64 + row) * SB + kt * 64 + cb;
            *(int4*)Ph = z;
            *(int4*)(Ph + 8) = z;
        }
        return;
    }

    __shared__ __align__(16) unsigned short Ql[64 * 128];
    __shared__ __align__(16) unsigned short Kl[64 * 128];

    const int q = qt * 64 + wv * 16 + l15;

    f32x4 zero4 = {0.f, 0.f, 0.f, 0.f};
    f32x4 cc[4];
#pragma unroll
    for (int c = 0; c < 4; ++c) cc[c] = zero4;

    for (int dc = 0; dc < 4; ++dc) {
        const int d0 = dc * 128;
        __syncthreads();
#pragma unroll
        for (int i = 0; i < 4; ++i) {
            int flat = (i * 256 + tid) * 8;
            int row = flat >> 7;
            int ch  = (flat >> 3) & 15;
            int scol = ((ch ^ (row & 15)) << 3);
            __builtin_amdgcn_global_load_lds(
                as_gbl(emb + ((size_t)(b * SB + qt * 64 + row)) * DD + d0 + scol),
                as_lds(Ql + flat), 16, 0, 0);
            __builtin_amdgcn_global_load_lds(
                as_gbl(emb + ((size_t)(b * SB + kt * 64 + row)) * DD + d0 + scol),
                as_lds(Kl + flat), 16, 0, 0);
        }
        asm volatile("s_waitcnt vmcnt(0)" ::: "memory");
        __syncthreads();

#pragma unroll
        for (int dsl = 0; dsl < 4; ++dsl) {
            int chr = (dsl * 4 + g);
            bf16x8 qf = *(const bf16x8*)(Ql + (wv * 16 + l15) * 128 + ((chr ^ l15) << 3));
#pragma unroll
            for (int c = 0; c < 4; ++c) {
                bf16x8 kf = *(const bf16x8*)(Kl + (c * 16 + l15) * 128 + ((chr ^ l15) << 3));
                cc[c] = __builtin_amdgcn_mfma_f32_16x16x32_bf16(kf, qf, cc[c], 0, 0, 0);
            }
        }
    }

    unsigned long long padm = __ballot(pad[(size_t)b * SB + kt * 64 + lane] != 0);

    const int wins[4] = {1 << 30, 128, 512, 1 << 30};
#pragma unroll
    for (int h = 0; h < 4; ++h) {
        const int win = wins[h];
        if (kt * 64 + win + 192 < qt * 64) continue;
        const float sf = sfs[h];
        const float* dth = dtab + h * SB;
        float rsum = 0.f;
        unsigned short pb[4][4];
#pragma unroll
        for (int c = 0; c < 4; ++c) {
#pragma unroll
            for (int r = 0; r < 4; ++r) {
                int kk = kt * 64 + c * 16 + 4 * g + r;
                int dist = q - kk;
                float p = 0.f;
                if (dist >= 0 && dist <= win &&
                    ((dist == 0) || !((padm >> (c * 16 + 4 * g + r)) & 1ull))) {
                    float s = cc[c][r] * dth[dist];
                    if (dist == 0) s *= sf;
                    p = __expf(s);
                }
                rsum += p;
                pb[c][r] = f2bf(p);
            }
        }
        unsigned short* Ph = P + (((size_t)(h * 2 + b)) * SB + q) * SB + kt * 64;
#pragma unroll
        for (int c = 0; c < 4; ++c) {
            us4 o;
            o.x = pb[c][0]; o.y = pb[c][1]; o.z = pb[c][2]; o.w = pb[c][3];
            *(us4*)(Ph + c * 16 + 4 * g) = o;
        }
        rsum += __shfl_xor(rsum, 16, 64);
        rsum += __shfl_xor(rsum, 32, 64);
        if (lane < 16)
            atomicAdd(&lsum[((size_t)(h * 2 + b)) * SB + q], rsum);
    }
}

// ---------------- phase 3: ctx = P * V^T, normalize, write concat ----------------
__launch_bounds__(256, 2)
__global__ void k_pv(const unsigned short* __restrict__ P,
                     const unsigned short* __restrict__ embT,
                     const float* __restrict__ lsum,
                     unsigned short* __restrict__ concat)
{
    const int t64 = blockIdx.x, b = blockIdx.y, h = blockIdx.z;
    const int mt = t64 >> 2, nt = t64 & 3;
    const int Q0 = mt * 128;
    const int win = (h == 1) ? 128 : (h == 2) ? 512 : (1 << 30);
    int klo = Q0 - win - 64; if (klo < 0) klo = 0; klo &= ~63;
    const int khi = Q0 + 128;

    __shared__ __align__(16) unsigned short Al[128 * 32];
    __shared__ __align__(16) unsigned short Bl[128 * 32];

    const int tid = threadIdx.x, lane = tid & 63, wv = tid >> 6;
    const int wm = (wv >> 1) * 64, wn = (wv & 1) * 64;
    const int l15 = lane & 15, g = lane >> 4;

    f32x4 zero4 = {0.f, 0.f, 0.f, 0.f};
    f32x4 acc[4][4];
#pragma unroll
    for (int i = 0; i < 4; ++i)
#pragma unroll
        for (int j = 0; j < 4; ++j) acc[i][j] = zero4;

    const unsigned short* Ab = P + (((size_t)(h * 2 + b)) * SB + Q0) * SB;
    const unsigned short* Bb = embT + ((size_t)(b * DD + nt * 128)) * SB;

    for (int k0 = klo; k0 < khi; k0 += 32) {
        __syncthreads();
#pragma unroll
        for (int s = 0; s < 2; ++s) {
            int e = (s * 256 + tid) * 8;
            int row = e >> 5, col = e & 31;
            __builtin_amdgcn_global_load_lds(as_gbl(Ab + (size_t)row * SB + k0 + col),
                                             as_lds(Al + e), 16, 0, 0);
            __builtin_amdgcn_global_load_lds(as_gbl(Bb + (size_t)row * SB + k0 + col),
                                             as_lds(Bl + e), 16, 0, 0);
        }
        asm volatile("s_waitcnt vmcnt(0)" ::: "memory");
        __syncthreads();

        bf16x8 af[4], bfr[4];
#pragma unroll
        for (int i = 0; i < 4; ++i) {
            af[i]  = *(const bf16x8*)(Al + (wm + i * 16 + l15) * 32 + 8 * g);
            bfr[i] = *(const bf16x8*)(Bl + (wn + i * 16 + l15) * 32 + 8 * g);
        }
#pragma unroll
        for (int i = 0; i < 4; ++i)
#pragma unroll
            for (int j = 0; j < 4; ++j)
                acc[i][j] = __builtin_amdgcn_mfma_f32_16x16x32_bf16(af[i], bfr[j], acc[i][j], 0, 0, 0);
    }

    const float* ls = lsum + ((size_t)(h * 2 + b)) * SB;
    unsigned short* cb = concat + ((size_t)(b * SB)) * (HH * DD) + h * DD + nt * 128;
#pragma unroll
    for (int i = 0; i < 4; ++i) {
        int rowb = wm + i * 16 + g * 4;
        float inv[4];
#pragma unroll
        for (int rr = 0; rr < 4; ++rr) inv[rr] = 1.f / ls[Q0 + rowb + rr];
#pragma unroll
        for (int j = 0; j < 4; ++j) {
            int col = wn + j * 16 + l15;
#pragma unroll
            for (int rr = 0; rr < 4; ++rr)
                cb[(size_t)(Q0 + rowb + rr) * (HH * DD) + col] = f2bf(acc[i][j][rr] * inv[rr]);
        }
    }
}

// ---------------- m97-style 128x128 GEMM (fusion GEMM) ----------------
template <int OUTF32>
__launch_bounds__(256, 2)
__global__ void k_gemm_bt(const unsigned short* __restrict__ A,
                          const unsigned short* __restrict__ Bt,
                          const float* __restrict__ bias,
                          void* __restrict__ Cout,
                          int M, int N, int K)
{
    const int nMt = M >> 7;
    const int nwg = gridDim.x;
    int bid = blockIdx.x;
    int q = nwg >> 3, r = nwg & 7;
    int x = bid & 7, o = bid >> 3;
    int wg = (x < r ? x * (q + 1) : r * (q + 1) + (x - r) * q) + o;
    const int mt = wg % nMt, nt = wg / nMt;

    __shared__ __align__(16) unsigned short Al[128 * 32];
    __shared__ __align__(16) unsigned short Bl[128 * 32];

    const int tid = threadIdx.x;
    const int lane = tid & 63;
    const int wv = tid >> 6;
    const int wm = (wv >> 1) * 64, wn = (wv & 1) * 64;
    const int l15 = lane & 15, g = lane >> 4;

    f32x4 zero4 = {0.f, 0.f, 0.f, 0.f};
    f32x4 acc[4][4];
#pragma unroll
    for (int i = 0; i < 4; ++i)
#pragma unroll
        for (int j = 0; j < 4; ++j) acc[i][j] = zero4;

    const unsigned short* Ab = A + (size_t)mt * 128 * K;
    const unsigned short* Bb = Bt + (size_t)nt * 128 * K;

    for (int k0 = 0; k0 < K; k0 += 32) {
        __syncthreads();
#pragma unroll
        for (int s = 0; s < 2; ++s) {
            int e = (s * 256 + tid) * 8;
            int row = e >> 5, col = e & 31;
            __builtin_amdgcn_global_load_lds(as_gbl(Ab + (size_t)row * K + k0 + col),
                                             as_lds(Al + e), 16, 0, 0);
            __builtin_amdgcn_global_load_lds(as_gbl(Bb + (size_t)row * K + k0 + col),
                                             as_lds(Bl + e), 16, 0, 0);
        }
        asm volatile("s_waitcnt vmcnt(0)" ::: "memory");
        __syncthreads();

        bf16x8 af[4], bfr[4];
#pragma unroll
        for (int i = 0; i < 4; ++i) {
            af[i]  = *(const bf16x8*)(Al + (wm + i * 16 + l15) * 32 + 8 * g);
            bfr[i] = *(const bf16x8*)(Bl + (wn + i * 16 + l15) * 32 + 8 * g);
        }
#pragma unroll
        for (int i = 0; i < 4; ++i)
#pragma unroll
            for (int j = 0; j < 4; ++j)
                acc[i][j] = __builtin_amdgcn_mfma_f32_16x16x32_bf16(af[i], bfr[j], acc[i][j], 0, 0, 0);
    }

#pragma unroll
    for (int i = 0; i < 4; ++i) {
        int rowb = mt * 128 + wm + i * 16 + g * 4;
#pragma unroll
        for (int j = 0; j < 4; ++j) {
            int col = nt * 128 + wn + j * 16 + l15;
            float bv = bias[col];
            if (OUTF32) {
                float* C = (float*)Cout;
#pragma unroll
                for (int rr = 0; rr < 4; ++rr)
                    C[(size_t)(rowb + rr) * N + col] = acc[i][j][rr] + bv;
            } else {
                unsigned short* C = (unsigned short*)Cout;
#pragma unroll
                for (int rr = 0; rr < 4; ++rr)
                    C[(size_t)(rowb + rr) * N + col] = f2bf(acc[i][j][rr] + bv);
            }
        }
    }
}

// ---------------- logits GEMM v5: m97-structure 256x256, BK=32, 32KB LDS, TLP ----------------
// 512 threads = 8 waves (2Mr x 4Nc of 128x64). No explicit dbuf: cross-block overlap.
__launch_bounds__(512, 2)
__global__ void k_logits(const unsigned short* __restrict__ A,
                         const unsigned short* __restrict__ Bt,
                         const float* __restrict__ bias,
                         float* __restrict__ Cout,
                         int M, int N, int K)
{
    const int nMt = M >> 8;
    const int nwg = gridDim.x;
    int bid = blockIdx.x;
    int q = nwg >> 3, r = nwg & 7;
    int x = bid & 7, o = bid >> 3;
    int wg = (x < r ? x * (q + 1) : r * (q + 1) + (x - r) * q) + o;
    const int mt = wg % nMt, nt = wg / nMt;

    __shared__ __align__(16) char smem[33024];   // staging 32KB; epilogue 33KB

    const int tid = threadIdx.x, lane = tid & 63, wv = tid >> 6;
    const int wr = wv >> 2, wc = wv & 3;
    const int l15 = lane & 15, g = lane >> 4;

    f32x4 zero4 = {0.f, 0.f, 0.f, 0.f};
    f32x4 acc[8][4];
#pragma unroll
    for (int i = 0; i < 8; ++i)
#pragma unroll
        for (int j = 0; j < 4; ++j) acc[i][j] = zero4;

    const unsigned short* Ab = A + (size_t)mt * 256 * K;
    const unsigned short* Bb = Bt + (size_t)nt * 256 * K;

    // staging: 256x32 tile = 1024 16B-chunks per operand, 2 per thread.
    // LDS dest linear; source column inverse-swizzled (2-bit XOR within 4-chunk row).
    const unsigned short* As[2];
    const unsigned short* Bs[2];
    int ldstA[2], ldstB[2];
#pragma unroll
    for (int j = 0; j < 2; ++j) {
        int ch = tid + j * 512;
        int row = ch >> 2, cpos = ch & 3;
        int scol = ((cpos ^ (row & 3)) << 3);
        As[j] = Ab + (size_t)row * K + scol;
        Bs[j] = Bb + (size_t)row * K + scol;
        ldstA[j] = ch * 16;            // bytes, A at [0,16384)
        ldstB[j] = 16384 + ch * 16;    // B at [16384,32768)
    }

    for (int k0 = 0; k0 < K; k0 += 32) {
        __syncthreads();
#pragma unroll
        for (int j = 0; j < 2; ++j) {
            __builtin_amdgcn_global_load_lds(as_gbl(As[j] + k0), as_lds(smem + ldstA[j]), 16, 0, 0);
            __builtin_amdgcn_global_load_lds(as_gbl(Bs[j] + k0), as_lds(smem + ldstB[j]), 16, 0, 0);
        }
        asm volatile("s_waitcnt vmcnt(0)" ::: "memory");
        __syncthreads();

        const unsigned short* Ar = (const unsigned short*)smem;
        const unsigned short* Br = (const unsigned short*)(smem + 16384);
        bf16x8 bf[4], af[8];
#pragma unroll
        for (int n = 0; n < 4; ++n)
            bf[n] = ldsrd32(Br, wc * 64 + n * 16 + l15, g);
#pragma unroll
        for (int m = 0; m < 8; ++m)
            af[m] = ldsrd32(Ar, wr * 128 + m * 16 + l15, g);
        __builtin_amdgcn_s_setprio(1);
#pragma unroll
        for (int m = 0; m < 8; ++m)
#pragma unroll
            for (int n = 0; n < 4; ++n)
                acc[m][n] = __builtin_amdgcn_mfma_f32_16x16x32_bf16(af[m], bf[n], acc[m][n], 0, 0, 0);
        __builtin_amdgcn_s_setprio(0);
    }

    // ---- epilogue: LDS-staged, full-line coalesced f32 stores ----
    __syncthreads();
    const int mrow = mt * 256;
    const int ncol = nt * 256;
    float* Cl = (float*)smem;
    float bvj[4];
#pragma unroll
    for (int j = 0; j < 4; ++j) bvj[j] = bias[ncol + wc * 64 + j * 16 + l15];
    const int srow = tid >> 4;            // 0..31
    const int scol = (tid & 15) * 4;      // 0..60 step 4
    const float* Crd = Cl + srow * 258 + scol;
#pragma unroll
    for (int mc = 0; mc < 8; ++mc) {
        if (wr == (mc >> 2)) {
            int ibase = (mc & 3) * 2;
#pragma unroll
            for (int ii = 0; ii < 2; ++ii) {
                int i = ibase + ii;
                int lr = ii * 16 + g * 4;
#pragma unroll
                for (int j = 0; j < 4; ++j)
#pragma unroll
                    for (int rr = 0; rr < 4; ++rr)
                        Cl[(lr + rr) * 258 + wc * 64 + j * 16 + l15] = acc[i][j][rr] + bvj[j];
            }
        }
        __syncthreads();
        {
            float* gp = Cout + (size_t)(mrow + mc * 32 + srow) * N + ncol + scol;
#pragma unroll
            for (int it = 0; it < 4; ++it)
                *(float4*)(gp + it * 64) = *(const float4*)(Crd + it * 64);
        }
        __syncthreads();
    }
}

extern "C" void kernel_launch(void* const* d_in, const int* in_sizes, int n_in,
                              void* d_out, int out_size, void* d_ws, size_t ws_size,
                              hipStream_t stream)
{
    const int*           ids = (const int*)d_in[0];
    const unsigned char* pad = (const unsigned char*)d_in[1];
    const float*         tbl = (const float*)d_in[2];
    const float*         sfs = (const float*)d_in[3];
    const float*         als = (const float*)d_in[4];
    const float*         fw  = (const float*)d_in[5];
    const float*         fb  = (const float*)d_in[6];
    const float*         ow  = (const float*)d_in[7];
    const float*         ob  = (const float*)d_in[8];
    float* logits = (float*)d_out;

    // d_ws layout (60 MB)
    char* ws = (char*)d_ws;
    unsigned short* outw_bf = (unsigned short*)(ws);              // 32,768,000 B
    unsigned short* fusw_bf = (unsigned short*)(ws + 32768000);   //  2,097,152 B
    unsigned short* emb_bf  = (unsigned short*)(ws + 34865152);   //  4,194,304 B
    unsigned short* concat  = (unsigned short*)(ws + 39059456);   // 16,777,216 B
    unsigned short* fused   = (unsigned short*)(ws + 55836672);   //  4,194,304 B

    // scratch inside d_out (dead until final GEMM overwrites it)
    char* ob_scratch = (char*)d_out;
    unsigned short* P    = (unsigned short*)(ob_scratch);              // 67,108,864 B
    unsigned short* embT = (unsigned short*)(ob_scratch + 67108864);   //  4,194,304 B
    float*          dtab = (float*)(ob_scratch + 71303168);            //     32,768 B
    float*          lsum = (float*)(ob_scratch + 71335936);            //     65,536 B

    k_prep<<<6960, 256, 0, stream>>>(ids, tbl, als, fw, ow,
                                     outw_bf, fusw_bf, emb_bf, embT, dtab, lsum);

    dim3 bg(32, 32, BB);
    k_base<<<bg, 256, 0, stream>>>(emb_bf, pad, sfs, dtab, P, lsum);

    dim3 pg(64, BB, HH);
    k_pv<<<pg, 256, 0, stream>>>(P, embT, lsum, concat);

    k_gemm_bt<0><<<32 * 4, 256, 0, stream>>>(concat, fusw_bf, fb, fused, BB * SB, DD, HH * DD);
    k_logits<<<16 * 125, 512, 0, stream>>>(fused, outw_bf, ob, logits, BB * SB, VV, DD);
}

// Round 10
// 401.284 us; speedup vs baseline: 1.4536x; 1.1220x over previous
//
#include <hip/hip_runtime.h>
#include <hip/hip_bf16.h>
#include <stdint.h>

#define BB 2
#define SB 2048
#define DD 512
#define HH 4
#define VV 32000

typedef __attribute__((ext_vector_type(4))) float f32x4;
typedef __attribute__((ext_vector_type(8))) short bf16x8;
typedef __attribute__((ext_vector_type(4))) unsigned short us4;

__device__ __forceinline__ unsigned short f2bf(float f) {
    unsigned u = __float_as_uint(f);
    u += 0x7fffu + ((u >> 16) & 1u);
    return (unsigned short)(u >> 16);
}

__device__ __forceinline__ __attribute__((address_space(3))) unsigned int*
as_lds(void* p) {
    return (__attribute__((address_space(3))) unsigned int*)(unsigned)(uintptr_t)p;
}
__device__ __forceinline__ const __attribute__((address_space(1))) unsigned int*
as_gbl(const void* p) {
    return (const __attribute__((address_space(1))) unsigned int*)(uintptr_t)p;
}

// ---------------- merged prep kernel ----------------
__global__ void k_prep(const int* __restrict__ ids, const float* __restrict__ tbl,
                       const float* __restrict__ als,
                       const float* __restrict__ fw, const float* __restrict__ ow,
                       unsigned short* __restrict__ outw_bf, unsigned short* __restrict__ fusw_bf,
                       unsigned short* __restrict__ emb, unsigned short* __restrict__ embT,
                       float* __restrict__ dtab, float* __restrict__ lsum)
{
    __shared__ unsigned short TT[64][72];
    const int bid = blockIdx.x, t = threadIdx.x;

    if (bid < 2000) {
        int base = bid * 8192 + t * 4;
#pragma unroll
        for (int it = 0; it < 8; ++it) {
            int i = base + it * 1024;
            float4 v = *(const float4*)(ow + i);
            us4 o; o.x = f2bf(v.x); o.y = f2bf(v.y); o.z = f2bf(v.z); o.w = f2bf(v.w);
            *(us4*)(outw_bf + i) = o;
        }
    } else if (bid < 2256) {
        int base = (bid - 2000) * 4096 + t * 4;
#pragma unroll
        for (int it = 0; it < 4; ++it) {
            int i = base + it * 1024;
            float4 v = *(const float4*)(fw + i);
            us4 o; o.x = f2bf(v.x); o.y = f2bf(v.y); o.z = f2bf(v.z); o.w = f2bf(v.w);
            *(us4*)(fusw_bf + i) = o;
        }
    } else if (bid < 6352) {
        int row = bid - 2256;
        int id = ids[row];
        if (id < 0) id = 0;
        if (id >= VV) id = VV - 1;
        const float* s = tbl + (size_t)id * DD;
        unsigned short* d = emb + (size_t)row * DD;
        d[t]       = f2bf(s[t]);
        d[t + 256] = f2bf(s[t + 256]);
    } else if (bid < 6448) {
        int i = (bid - 6352) * 256 + t;
        if (i < HH * SB) {
            int h = i >> 11, dd = i & (SB - 1);
            dtab[i] = 0.04419417382415922f / (1.f + als[h] * (float)dd);
        } else {
            lsum[i - HH * SB] = 0.f;
        }
    } else {
        int bid2 = bid - 6448;
        const int d0 = (bid2 & 7) * 64, s0 = ((bid2 >> 3) & 31) * 64, b = bid2 >> 8;
        {
            int s = t >> 2, c16 = (t & 3) * 16;
            int id = ids[b * SB + s0 + s];
            if (id < 0) id = 0;
            if (id >= VV) id = VV - 1;
            const float* src = tbl + (size_t)id * DD + d0 + c16;
#pragma unroll
            for (int q4 = 0; q4 < 4; ++q4) {
                float4 v = *(const float4*)(src + q4 * 4);
                TT[c16 + q4 * 4 + 0][s] = f2bf(v.x);
                TT[c16 + q4 * 4 + 1][s] = f2bf(v.y);
                TT[c16 + q4 * 4 + 2][s] = f2bf(v.z);
                TT[c16 + q4 * 4 + 3][s] = f2bf(v.w);
            }
        }
        __syncthreads();
        {
            int d = t >> 2, sc = (t & 3) * 16;
            bf16x8 o0, o1;
#pragma unroll
            for (int j = 0; j < 8; ++j) {
                o0[j] = (short)TT[d][sc + j];
                o1[j] = (short)TT[d][sc + 8 + j];
            }
            unsigned short* dst = embT + ((size_t)(b * DD + d0 + d)) * SB + s0 + sc;
            *(bf16x8*)dst = o0;
            *(bf16x8*)(dst + 8) = o1;
        }
    }
}

// ---------------- phase 2: shared base QK^T -> per-head P tiles + row sums ----------------
__launch_bounds__(256, 2)
__global__ void k_base(const unsigned short* __restrict__ emb,
                       const unsigned char* __restrict__ pad,
                       const float* __restrict__ sfs,
                       const float* __restrict__ dtab,
                       unsigned short* __restrict__ P,      // [4][2][2048][2048]
                       float* __restrict__ lsum)            // [4][2][2048]
{
    const int kt = blockIdx.x, qt = blockIdx.y, b = blockIdx.z;
    if (kt > qt + 1) return;
    const int tid = threadIdx.x, lane = tid & 63, wv = tid >> 6;
    const int l15 = lane & 15, g = lane >> 4;

    if (kt == qt + 1) {
        int row = tid >> 2, cb = (tid & 3) * 16;
        int4 z = {0, 0, 0, 0};
#pragma unroll
        for (int h = 0; h < 4; ++h) {
            unsigned short* Ph = P + (((size_t)(h * 2 + b)) * SB + qt * 64 + row) * SB + kt * 64 + cb;
            *(int4*)Ph = z;
            *(int4*)(Ph + 8) = z;
        }
        return;
    }

    __shared__ __align__(16) unsigned short Ql[64 * 128];
    __shared__ __align__(16) unsigned short Kl[64 * 128];

    const int q = qt * 64 + wv * 16 + l15;

    f32x4 zero4 = {0.f, 0.f, 0.f, 0.f};
    f32x4 cc[4];
#pragma unroll
    for (int c = 0; c < 4; ++c) cc[c] = zero4;

    for (int dc = 0; dc < 4; ++dc) {
        const int d0 = dc * 128;
        __syncthreads();
#pragma unroll
        for (int i = 0; i < 4; ++i) {
            int flat = (i * 256 + tid) * 8;
            int row = flat >> 7;
            int ch  = (flat >> 3) & 15;
            int scol = ((ch ^ (row & 15)) << 3);
            __builtin_amdgcn_global_load_lds(
                as_gbl(emb + ((size_t)(b * SB + qt * 64 + row)) * DD + d0 + scol),
                as_lds(Ql + flat), 16, 0, 0);
            __builtin_amdgcn_global_load_lds(
                as_gbl(emb + ((size_t)(b * SB + kt * 64 + row)) * DD + d0 + scol),
                as_lds(Kl + flat), 16, 0, 0);
        }
        asm volatile("s_waitcnt vmcnt(0)" ::: "memory");
        __syncthreads();

#pragma unroll
        for (int dsl = 0; dsl < 4; ++dsl) {
            int chr = (dsl * 4 + g);
            bf16x8 qf = *(const bf16x8*)(Ql + (wv * 16 + l15) * 128 + ((chr ^ l15) << 3));
#pragma unroll
            for (int c = 0; c < 4; ++c) {
                bf16x8 kf = *(const bf16x8*)(Kl + (c * 16 + l15) * 128 + ((chr ^ l15) << 3));
                cc[c] = __builtin_amdgcn_mfma_f32_16x16x32_bf16(kf, qf, cc[c], 0, 0, 0);
            }
        }
    }

    unsigned long long padm = __ballot(pad[(size_t)b * SB + kt * 64 + lane] != 0);

    const int wins[4] = {1 << 30, 128, 512, 1 << 30};
#pragma unroll
    for (int h = 0; h < 4; ++h) {
        const int win = wins[h];
        if (kt * 64 + win + 192 < qt * 64) continue;
        const float sf = sfs[h];
        const float* dth = dtab + h * SB;
        float rsum = 0.f;
        unsigned short pb[4][4];
#pragma unroll
        for (int c = 0; c < 4; ++c) {
#pragma unroll
            for (int r = 0; r < 4; ++r) {
                int kk = kt * 64 + c * 16 + 4 * g + r;
                int dist = q - kk;
                float p = 0.f;
                if (dist >= 0 && dist <= win &&
                    ((dist == 0) || !((padm >> (c * 16 + 4 * g + r)) & 1ull))) {
                    float s = cc[c][r] * dth[dist];
                    if (dist == 0) s *= sf;
                    p = __expf(s);
                }
                rsum += p;
                pb[c][r] = f2bf(p);
            }
        }
        unsigned short* Ph = P + (((size_t)(h * 2 + b)) * SB + q) * SB + kt * 64;
#pragma unroll
        for (int c = 0; c < 4; ++c) {
            us4 o;
            o.x = pb[c][0]; o.y = pb[c][1]; o.z = pb[c][2]; o.w = pb[c][3];
            *(us4*)(Ph + c * 16 + 4 * g) = o;
        }
        rsum += __shfl_xor(rsum, 16, 64);
        rsum += __shfl_xor(rsum, 32, 64);
        if (lane < 16)
            atomicAdd(&lsum[((size_t)(h * 2 + b)) * SB + q], rsum);
    }
}

// ---------------- phase 3: ctx = P * V^T, normalize, write concat ----------------
__launch_bounds__(256, 2)
__global__ void k_pv(const unsigned short* __restrict__ P,
                     const unsigned short* __restrict__ embT,
                     const float* __restrict__ lsum,
                     unsigned short* __restrict__ concat)
{
    const int t64 = blockIdx.x, b = blockIdx.y, h = blockIdx.z;
    const int mt = t64 >> 2, nt = t64 & 3;
    const int Q0 = mt * 128;
    const int win = (h == 1) ? 128 : (h == 2) ? 512 : (1 << 30);
    int klo = Q0 - win - 64; if (klo < 0) klo = 0; klo &= ~63;
    const int khi = Q0 + 128;

    __shared__ __align__(16) unsigned short Al[128 * 32];
    __shared__ __align__(16) unsigned short Bl[128 * 32];

    const int tid = threadIdx.x, lane = tid & 63, wv = tid >> 6;
    const int wm = (wv >> 1) * 64, wn = (wv & 1) * 64;
    const int l15 = lane & 15, g = lane >> 4;

    f32x4 zero4 = {0.f, 0.f, 0.f, 0.f};
    f32x4 acc[4][4];
#pragma unroll
    for (int i = 0; i < 4; ++i)
#pragma unroll
        for (int j = 0; j < 4; ++j) acc[i][j] = zero4;

    const unsigned short* Ab = P + (((size_t)(h * 2 + b)) * SB + Q0) * SB;
    const unsigned short* Bb = embT + ((size_t)(b * DD + nt * 128)) * SB;

    for (int k0 = klo; k0 < khi; k0 += 32) {
        __syncthreads();
#pragma unroll
        for (int s = 0; s < 2; ++s) {
            int e = (s * 256 + tid) * 8;
            int row = e >> 5, col = e & 31;
            __builtin_amdgcn_global_load_lds(as_gbl(Ab + (size_t)row * SB + k0 + col),
                                             as_lds(Al + e), 16, 0, 0);
            __builtin_amdgcn_global_load_lds(as_gbl(Bb + (size_t)row * SB + k0 + col),
                                             as_lds(Bl + e), 16, 0, 0);
        }
        asm volatile("s_waitcnt vmcnt(0)" ::: "memory");
        __syncthreads();

        bf16x8 af[4], bfr[4];
#pragma unroll
        for (int i = 0; i < 4; ++i) {
            af[i]  = *(const bf16x8*)(Al + (wm + i * 16 + l15) * 32 + 8 * g);
            bfr[i] = *(const bf16x8*)(Bl + (wn + i * 16 + l15) * 32 + 8 * g);
        }
#pragma unroll
        for (int i = 0; i < 4; ++i)
#pragma unroll
            for (int j = 0; j < 4; ++j)
                acc[i][j] = __builtin_amdgcn_mfma_f32_16x16x32_bf16(af[i], bfr[j], acc[i][j], 0, 0, 0);
    }

    const float* ls = lsum + ((size_t)(h * 2 + b)) * SB;
    unsigned short* cb = concat + ((size_t)(b * SB)) * (HH * DD) + h * DD + nt * 128;
#pragma unroll
    for (int i = 0; i < 4; ++i) {
        int rowb = wm + i * 16 + g * 4;
        float inv[4];
#pragma unroll
        for (int rr = 0; rr < 4; ++rr) inv[rr] = 1.f / ls[Q0 + rowb + rr];
#pragma unroll
        for (int j = 0; j < 4; ++j) {
            int col = wn + j * 16 + l15;
#pragma unroll
            for (int rr = 0; rr < 4; ++rr)
                cb[(size_t)(Q0 + rowb + rr) * (HH * DD) + col] = f2bf(acc[i][j][rr] * inv[rr]);
        }
    }
}

// ---------------- m97-style 128x128 GEMM (fusion GEMM) ----------------
template <int OUTF32>
__launch_bounds__(256, 2)
__global__ void k_gemm_bt(const unsigned short* __restrict__ A,
                          const unsigned short* __restrict__ Bt,
                          const float* __restrict__ bias,
                          void* __restrict__ Cout,
                          int M, int N, int K)
{
    const int nMt = M >> 7;
    const int nwg = gridDim.x;
    int bid = blockIdx.x;
    int q = nwg >> 3, r = nwg & 7;
    int x = bid & 7, o = bid >> 3;
    int wg = (x < r ? x * (q + 1) : r * (q + 1) + (x - r) * q) + o;
    const int mt = wg % nMt, nt = wg / nMt;

    __shared__ __align__(16) unsigned short Al[128 * 32];
    __shared__ __align__(16) unsigned short Bl[128 * 32];

    const int tid = threadIdx.x;
    const int lane = tid & 63;
    const int wv = tid >> 6;
    const int wm = (wv >> 1) * 64, wn = (wv & 1) * 64;
    const int l15 = lane & 15, g = lane >> 4;

    f32x4 zero4 = {0.f, 0.f, 0.f, 0.f};
    f32x4 acc[4][4];
#pragma unroll
    for (int i = 0; i < 4; ++i)
#pragma unroll
        for (int j = 0; j < 4; ++j) acc[i][j] = zero4;

    const unsigned short* Ab = A + (size_t)mt * 128 * K;
    const unsigned short* Bb = Bt + (size_t)nt * 128 * K;

    for (int k0 = 0; k0 < K; k0 += 32) {
        __syncthreads();
#pragma unroll
        for (int s = 0; s < 2; ++s) {
            int e = (s * 256 + tid) * 8;
            int row = e >> 5, col = e & 31;
            __builtin_amdgcn_global_load_lds(as_gbl(Ab + (size_t)row * K + k0 + col),
                                             as_lds(Al + e), 16, 0, 0);
            __builtin_amdgcn_global_load_lds(as_gbl(Bb + (size_t)row * K + k0 + col),
                                             as_lds(Bl + e), 16, 0, 0);
        }
        asm volatile("s_waitcnt vmcnt(0)" ::: "memory");
        __syncthreads();

        bf16x8 af[4], bfr[4];
#pragma unroll
        for (int i = 0; i < 4; ++i) {
            af[i]  = *(const bf16x8*)(Al + (wm + i * 16 + l15) * 32 + 8 * g);
            bfr[i] = *(const bf16x8*)(Bl + (wn + i * 16 + l15) * 32 + 8 * g);
        }
#pragma unroll
        for (int i = 0; i < 4; ++i)
#pragma unroll
            for (int j = 0; j < 4; ++j)
                acc[i][j] = __builtin_amdgcn_mfma_f32_16x16x32_bf16(af[i], bfr[j], acc[i][j], 0, 0, 0);
    }

#pragma unroll
    for (int i = 0; i < 4; ++i) {
        int rowb = mt * 128 + wm + i * 16 + g * 4;
#pragma unroll
        for (int j = 0; j < 4; ++j) {
            int col = nt * 128 + wn + j * 16 + l15;
            float bv = bias[col];
            if (OUTF32) {
                float* C = (float*)Cout;
#pragma unroll
                for (int rr = 0; rr < 4; ++rr)
                    C[(size_t)(rowb + rr) * N + col] = acc[i][j][rr] + bv;
            } else {
                unsigned short* C = (unsigned short*)Cout;
#pragma unroll
                for (int rr = 0; rr < 4; ++rr)
                    C[(size_t)(rowb + rr) * N + col] = f2bf(acc[i][j][rr] + bv);
            }
        }
    }
}

// ---------------- logits GEMM v6: 256x256 tile, ring-4 over 32-K-chunks, 8-phase ----------
// 512 thr = 8 waves (wr 2 x wc 4, per-wave 128x64). Counted vmcnt(8), setprio, swizzle.
__launch_bounds__(512, 1)
__global__ void k_logits(const unsigned short* __restrict__ A,
                         const unsigned short* __restrict__ Bt,
                         const float* __restrict__ bias,
                         float* __restrict__ Cout,
                         int M, int N, int K)
{
    const int nMt = M >> 8;
    const int nwg = gridDim.x;
    int bid = blockIdx.x;
    int q = nwg >> 3, r = nwg & 7;
    int x = bid & 7, o = bid >> 3;
    int wg = (x < r ? x * (q + 1) : r * (q + 1) + (x - r) * q) + o;
    const int mt = wg % nMt, nt = wg / nMt;

    __shared__ __align__(16) char smem[131072];   // A ring [0,64K), B ring [64K,128K)

    const int tid = threadIdx.x, lane = tid & 63, wv = tid >> 6;
    const int wr = wv >> 2, wc = wv & 3;
    const int l15 = lane & 15, g = lane >> 4;

    f32x4 zero4 = {0.f, 0.f, 0.f, 0.f};
    f32x4 acc[8][4];
#pragma unroll
    for (int i = 0; i < 8; ++i)
#pragma unroll
        for (int j = 0; j < 4; ++j) acc[i][j] = zero4;

    // staging: chunk unit = [256 rows][32 K] = 1024 x 16B; 2 chunks16/thread.
    const int chs0 = tid, chs1 = tid + 512;
    const int sr0 = chs0 >> 2, sp0 = chs0 & 3;
    const int sr1 = chs1 >> 2, sp1 = chs1 & 3;
    const int sc0 = ((sp0 ^ ((sr0 >> 2) & 3)) << 3);  // inverse-swizzled source col
    const int sc1 = ((sp1 ^ ((sr1 >> 2) & 3)) << 3);
    const unsigned short* A0 = A + (size_t)(mt * 256 + sr0) * K + sc0;
    const unsigned short* A1 = A + (size_t)(mt * 256 + sr1) * K + sc1;
    const unsigned short* B0 = Bt + (size_t)(nt * 256 + sr0) * K + sc0;
    const unsigned short* B1 = Bt + (size_t)(nt * 256 + sr1) * K + sc1;

#define STA(c_) { int s_ = (c_) & 3;                                                        \
    __builtin_amdgcn_global_load_lds(as_gbl(A0 + (c_) * 32), as_lds(smem + s_ * 16384 + chs0 * 16), 16, 0, 0); \
    __builtin_amdgcn_global_load_lds(as_gbl(A1 + (c_) * 32), as_lds(smem + s_ * 16384 + chs1 * 16), 16, 0, 0); }
#define STB(c_) { int s_ = (c_) & 3;                                                        \
    __builtin_amdgcn_global_load_lds(as_gbl(B0 + (c_) * 32), as_lds(smem + 65536 + s_ * 16384 + chs0 * 16), 16, 0, 0); \
    __builtin_amdgcn_global_load_lds(as_gbl(B1 + (c_) * 32), as_lds(smem + 65536 + s_ * 16384 + chs1 * 16), 16, 0, 0); }
#define RDA(s_, m_) (*(const bf16x8*)(smem + (s_) * 16384 +                                 \
    (wr * 128 + (m_) * 16 + l15) * 64 + ((g ^ (((wr * 128 + (m_) * 16 + l15) >> 2) & 3)) << 4)))
#define RDB(s_, n_) (*(const bf16x8*)(smem + 65536 + (s_) * 16384 +                         \
    (wc * 64 + (n_) * 16 + l15) * 64 + ((g ^ (((wc * 64 + (n_) * 16 + l15) >> 2) & 3)) << 4)))
#define MFMA16(mb_)                                                                          \
    _Pragma("unroll")                                                                        \
    for (int m_ = 0; m_ < 4; ++m_)                                                           \
        _Pragma("unroll")                                                                    \
        for (int n_ = 0; n_ < 4; ++n_)                                                       \
            acc[(mb_) + m_][n_] = __builtin_amdgcn_mfma_f32_16x16x32_bf16(                   \
                af[m_], bf[n_], acc[(mb_) + m_][n_], 0, 0, 0);

    // prologue: chunks 0,1,2 in flight; wait for chunk 0 (allow 8 younger)
    STA(0); STB(0); STA(1); STB(1); STA(2); STB(2);
    asm volatile("s_waitcnt vmcnt(8)" ::: "memory");
    __builtin_amdgcn_s_barrier();

    const int NC = K >> 5;   // 16
    for (int c = 0; c < NC; ++c) {
        const int s = c & 3;
        bf16x8 bf[4], af[4];
        // ---- phase 0: m0-3 x n0-3 (8 ds_read) ----
#pragma unroll
        for (int n = 0; n < 4; ++n) bf[n] = RDB(s, n);
#pragma unroll
        for (int m = 0; m < 4; ++m) af[m] = RDA(s, m);
        if (c + 3 < NC) STA(c + 3);
        __builtin_amdgcn_sched_barrier(0);
        __builtin_amdgcn_s_barrier();
        __builtin_amdgcn_sched_barrier(0);
        __builtin_amdgcn_s_setprio(1);
        MFMA16(0);
        __builtin_amdgcn_s_setprio(0);
        __builtin_amdgcn_sched_barrier(0);
        __builtin_amdgcn_s_barrier();
        __builtin_amdgcn_sched_barrier(0);
        // ---- phase 1: m4-7 x n0-3 (4 ds_read) ----
#pragma unroll
        for (int m = 0; m < 4; ++m) af[m] = RDA(s, m + 4);
        if (c + 3 < NC) STB(c + 3);
        __builtin_amdgcn_sched_barrier(0);
        __builtin_amdgcn_s_barrier();
        __builtin_amdgcn_sched_barrier(0);
        __builtin_amdgcn_s_setprio(1);
        MFMA16(4);
        __builtin_amdgcn_s_setprio(0);
        // boundary: counted vmcnt (never 0 until tail), then barrier
        if (c <= NC - 4)      { asm volatile("s_waitcnt vmcnt(8)" ::: "memory"); }
        else if (c == NC - 3) { asm volatile("s_waitcnt vmcnt(4)" ::: "memory"); }
        else if (c == NC - 2) { asm volatile("s_waitcnt vmcnt(0)" ::: "memory"); }
        __builtin_amdgcn_sched_barrier(0);
        __builtin_amdgcn_s_barrier();
        __builtin_amdgcn_sched_barrier(0);
    }
#undef STA
#undef STB
#undef RDA
#undef RDB
#undef MFMA16

    // ---- epilogue: LDS-staged, full-line coalesced f32 stores ----
    __syncthreads();
    const int mrow = mt * 256;
    const int ncol = nt * 256;
    float* Cl = (float*)smem;
    float bvj[4];
#pragma unroll
    for (int j = 0; j < 4; ++j) bvj[j] = bias[ncol + wc * 64 + j * 16 + l15];
    const int srow = tid >> 4;            // 0..31
    const int scol = (tid & 15) * 4;      // 0..60 step 4
    const float* Crd = Cl + srow * 258 + scol;
#pragma unroll
    for (int mc = 0; mc < 8; ++mc) {
        if (wr == (mc >> 2)) {
            int ibase = (mc & 3) * 2;
#pragma unroll
            for (int ii = 0; ii < 2; ++ii) {
                int i = ibase + ii;
                int lr = ii * 16 + g * 4;
#pragma unroll
                for (int j = 0; j < 4; ++j)
#pragma unroll
                    for (int rr = 0; rr < 4; ++rr)
                        Cl[(lr + rr) * 258 + wc * 64 + j * 16 + l15] = acc[i][j][rr] + bvj[j];
            }
        }
        __syncthreads();
        {
            float* gp = Cout + (size_t)(mrow + mc * 32 + srow) * N + ncol + scol;
#pragma unroll
            for (int it = 0; it < 4; ++it)
                *(float4*)(gp + it * 64) = *(const float4*)(Crd + it * 64);
        }
        __syncthreads();
    }
}

extern "C" void kernel_launch(void* const* d_in, const int* in_sizes, int n_in,
                              void* d_out, int out_size, void* d_ws, size_t ws_size,
                              hipStream_t stream)
{
    const int*           ids = (const int*)d_in[0];
    const unsigned char* pad = (const unsigned char*)d_in[1];
    const float*         tbl = (const float*)d_in[2];
    const float*         sfs = (const float*)d_in[3];
    const float*         als = (const float*)d_in[4];
    const float*         fw  = (const float*)d_in[5];
    const float*         fb  = (const float*)d_in[6];
    const float*         ow  = (const float*)d_in[7];
    const float*         ob  = (const float*)d_in[8];
    float* logits = (float*)d_out;

    // d_ws layout (60 MB)
    char* ws = (char*)d_ws;
    unsigned short* outw_bf = (unsigned short*)(ws);              // 32,768,000 B
    unsigned short* fusw_bf = (unsigned short*)(ws + 32768000);   //  2,097,152 B
    unsigned short* emb_bf  = (unsigned short*)(ws + 34865152);   //  4,194,304 B
    unsigned short* concat  = (unsigned short*)(ws + 39059456);   // 16,777,216 B
    unsigned short* fused   = (unsigned short*)(ws + 55836672);   //  4,194,304 B

    // scratch inside d_out (dead until final GEMM overwrites it)
    char* ob_scratch = (char*)d_out;
    unsigned short* P    = (unsigned short*)(ob_scratch);              // 67,108,864 B
    unsigned short* embT = (unsigned short*)(ob_scratch + 67108864);   //  4,194,304 B
    float*          dtab = (float*)(ob_scratch + 71303168);            //     32,768 B
    float*          lsum = (float*)(ob_scratch + 71335936);            //     65,536 B

    k_prep<<<6960, 256, 0, stream>>>(ids, tbl, als, fw, ow,
                                     outw_bf, fusw_bf, emb_bf, embT, dtab, lsum);

    dim3 bg(32, 32, BB);
    k_base<<<bg, 256, 0, stream>>>(emb_bf, pad, sfs, dtab, P, lsum);

    dim3 pg(64, BB, HH);
    k_pv<<<pg, 256, 0, stream>>>(P, embT, lsum, concat);

    k_gemm_bt<0><<<32 * 4, 256, 0, stream>>>(concat, fusw_bf, fb, fused, BB * SB, DD, HH * DD);
    k_logits<<<16 * 125, 512, 0, stream>>>(fused, outw_bf, ob, logits, BB * SB, VV, DD);
}